// Round 5
// baseline (147.464 us; speedup 1.0000x reference)
//
#include <hip/hip_runtime.h>

#define B 32
#define E 256
#define N 64
#define KV 100
#define QD 768
#define WAVES 4

// ---------------------------------------------------------------------------
// Prep: blocks 0..31 -> Qk[b][j] = 0.1 * sum_i tanh(q[b]@W_q[i]+b_q[i]) * W_kv[i][j]
// ---------------------------------------------------------------------------
__global__ __launch_bounds__(256) void prep_kernel(
    const float* __restrict__ q,      // [B, QD]
    const float* __restrict__ W_q,    // [KV, QD]
    const float* __restrict__ b_q,    // [KV]
    const float* __restrict__ W_kv,   // [KV, KV]
    float* __restrict__ Qk)           // ws: [B, KV]
{
    const int tid = threadIdx.x;
    const int b   = blockIdx.x;

    __shared__ float q_lds[QD];
    __shared__ float Qp_lds[KV];

    for (int i = tid; i < QD; i += 256) q_lds[i] = q[b * QD + i];
    __syncthreads();

    // Qp[i] = tanh(dot(q[b], W_q[i]) + b_q[i]); 2 threads per output
    const int i = tid >> 1, h = tid & 1;
    if (i < KV) {
        float acc = 0.f;
        const float* wrow = W_q + i * QD + h * (QD / 2);
        const float* qrow = q_lds + h * (QD / 2);
        #pragma unroll 8
        for (int d = 0; d < QD / 2; d++) acc += qrow[d] * wrow[d];
        acc += __shfl_xor(acc, 1);
        if (h == 0) Qp_lds[i] = tanhf(acc + b_q[i]);
    }
    __syncthreads();

    // Qk[b][j] = (1/sqrt(KV)) * sum_i Qp[i] * W_kv[i][j]
    if (tid < KV) {
        float acc = 0.f;
        #pragma unroll 4
        for (int ii = 0; ii < KV; ii++) acc += Qp_lds[ii] * W_kv[ii * KV + tid];
        Qk[b * KV + tid] = acc * 0.1f;   // 1/sqrt(100)
    }
}

// ---------------------------------------------------------------------------
// Main: ONE WAVE per (b,e), ZERO barriers. Each resident wave is an
// independent job -> pure TLP latency hiding (the fillBuffer regime).
// Cross-phase data in per-wave LDS slices (within-wave deps = lgkmcnt only).
// ---------------------------------------------------------------------------
__global__ __launch_bounds__(256) void attn_kernel(
    const float* __restrict__ k,    // [B,E,N,KV]
    const float* __restrict__ v,    // [B,E,N,KV]
    const float* __restrict__ Qk,   // [B,KV] (pre-scaled by 1/sqrt(KV))
    const float* __restrict__ W_v,  // [KV,KV]
    float* __restrict__ out)        // [B,E,KV]
{
    __shared__ __align__(16) float qk_lds[WAVES][KV];
    __shared__ float att_lds[WAVES][N];
    __shared__ __align__(16) float agg_lds[WAVES][KV];

    const int tid  = threadIdx.x;
    const int wid  = tid >> 6;
    const int lane = tid & 63;
    const int be   = blockIdx.x * WAVES + wid;   // 0..B*E-1
    const int b    = be >> 8;                    // /E

    const float4* kbase = (const float4*)(k + (size_t)be * (N * KV));
    const float4* vbase = (const float4*)(v + (size_t)be * (N * KV));

    // ---- W0: Qk row -> per-wave LDS (one float4 per lane<25) ----
    if (lane < KV / 4)
        ((float4*)qk_lds[wid])[lane] = ((const float4*)(Qk + b * KV))[lane];

    // ---- W1: score for row n = lane; softmax fully in-wave ----
    {
        const float4* krow = kbase + lane * (KV / 4);
        const float4* qq4  = (const float4*)qk_lds[wid];
        float acc = 0.f;
        #pragma unroll
        for (int j = 0; j < KV / 4; j++) {
            float4 kk = krow[j];
            float4 qq = qq4[j];
            acc += qq.x * kk.x + qq.y * kk.y + qq.z * kk.z + qq.w * kk.w;
        }
        float a = acc;                       // already scaled by 1/sqrt(KV)
        if (a == 0.0f) a = -10000.0f;        // masked_fill(att==0, -1e4)
        a = (a > 0.0f) ? a : 0.01f * a;      // leaky_relu
        float m = a;
        #pragma unroll
        for (int o = 32; o; o >>= 1) m = fmaxf(m, __shfl_xor(m, o));
        float e = __expf(a - m);
        float s = e;
        #pragma unroll
        for (int o = 32; o; o >>= 1) s += __shfl_xor(s, o);
        float r = e / s;
        if (r == 0.015625f) r = 0.f;         // masked_fill(att==1/N, 0)
        att_lds[wid][lane] = r;
    }

    // ---- W2: agg[d] = sum_n att[n]*v[n,d]; 2 rows/iter, 50 lanes ----
    {
        const int c   = (lane < 25) ? lane : lane - 25;  // float4 column
        const int par = (lane < 25) ? 0 : 1;             // row parity
        float4 acc4 = make_float4(0.f, 0.f, 0.f, 0.f);
        if (lane < 50) {
            #pragma unroll
            for (int i = 0; i < N / 2; i++) {
                const int n = 2 * i + par;
                float4 vv = vbase[n * (KV / 4) + c];
                float  w  = att_lds[wid][n];   // 2-addr LDS broadcast
                acc4.x += w * vv.x;
                acc4.y += w * vv.y;
                acc4.z += w * vv.z;
                acc4.w += w * vv.w;
            }
        }
        // combine parities: lane l (<25) += lane l+25
        float ox = __shfl(acc4.x, lane + 25);
        float oy = __shfl(acc4.y, lane + 25);
        float oz = __shfl(acc4.z, lane + 25);
        float ow = __shfl(acc4.w, lane + 25);
        if (lane < 25) {
            acc4.x += ox; acc4.y += oy; acc4.z += oz; acc4.w += ow;
            ((float4*)agg_lds[wid])[lane] = acc4;
        }
    }

    // ---- W3: out[be][i] = dot(W_v row i, agg); two passes of 64 ----
    {
        const float4* wv4 = (const float4*)W_v;          // L1/L2-hot (40 KB)
        const float4* a4  = (const float4*)agg_lds[wid];
        #pragma unroll
        for (int p = 0; p < 2; p++) {
            const int i = p * 64 + lane;
            if (i < KV) {
                float acc = 0.f;
                #pragma unroll
                for (int j = 0; j < KV / 4; j++) {
                    float4 w = wv4[i * (KV / 4) + j];
                    float4 a = a4[j];                    // uniform broadcast
                    acc += w.x * a.x + w.y * a.y + w.z * a.z + w.w * a.w;
                }
                out[(size_t)be * KV + i] = acc;
            }
        }
    }
}

extern "C" void kernel_launch(void* const* d_in, const int* in_sizes, int n_in,
                              void* d_out, int out_size, void* d_ws, size_t ws_size,
                              hipStream_t stream) {
    // setup_inputs order: input_ent, q, k, v, W_q, b_q, W_kv, W_v
    const float* q    = (const float*)d_in[1];
    const float* k    = (const float*)d_in[2];
    const float* v    = (const float*)d_in[3];
    const float* W_q  = (const float*)d_in[4];
    const float* b_q  = (const float*)d_in[5];
    const float* W_kv = (const float*)d_in[6];
    const float* W_v  = (const float*)d_in[7];
    float* out  = (float*)d_out;

    float* Qk = (float*)d_ws;            // B*KV = 3200 floats

    prep_kernel<<<B, 256, 0, stream>>>(q, W_q, b_q, W_kv, Qk);
    attn_kernel<<<(B * E) / WAVES, 256, 0, stream>>>(k, v, Qk, W_v, out);
}

// Round 6
// 104.891 us; speedup vs baseline: 1.4059x; 1.4059x over previous
//
#include <hip/hip_runtime.h>

#define B 32
#define E 256
#define N 64
#define KV 100
#define QD 768
#define NF4 ((N * KV) / 4)     // 1600 float4s per (b,e) tile
#define WF4 ((KV * KV) / 4)    // 2500 float4s of W_v

__device__ __forceinline__ float dot4(float4 a, float4 b) {
    return a.x * b.x + a.y * b.y + a.z * b.z + a.w * b.w;
}

// async global->LDS, 16B per lane; dst is wave-uniform base, src is per-lane
#define ASYNC16(gsrc, ldst) \
    __builtin_amdgcn_global_load_lds( \
        (const __attribute__((address_space(1))) void*)(gsrc), \
        (__attribute__((address_space(3))) void*)(ldst), 16, 0, 0)

// ---------------------------------------------------------------------------
// Prep: blocks 0..31 -> Qk[b][j] = 0.1 * sum_i tanh(q[b]@W_q[i]+b_q[i]) * W_kv[i][j]
// ---------------------------------------------------------------------------
__global__ __launch_bounds__(256) void prep_kernel(
    const float* __restrict__ q,      // [B, QD]
    const float* __restrict__ W_q,    // [KV, QD]
    const float* __restrict__ b_q,    // [KV]
    const float* __restrict__ W_kv,   // [KV, KV]
    float* __restrict__ Qk)           // ws: [B, KV]
{
    const int tid = threadIdx.x;
    const int b   = blockIdx.x;

    __shared__ float q_lds[QD];
    __shared__ float Qp_lds[KV];

    for (int i = tid; i < QD; i += 256) q_lds[i] = q[b * QD + i];
    __syncthreads();

    const int i = tid >> 1, h = tid & 1;
    if (i < KV) {
        float acc = 0.f;
        const float* wrow = W_q + i * QD + h * (QD / 2);
        const float* qrow = q_lds + h * (QD / 2);
        #pragma unroll 8
        for (int d = 0; d < QD / 2; d++) acc += qrow[d] * wrow[d];
        acc += __shfl_xor(acc, 1);
        if (h == 0) Qp_lds[i] = tanhf(acc + b_q[i]);
    }
    __syncthreads();

    if (tid < KV) {
        float acc = 0.f;
        #pragma unroll 4
        for (int ii = 0; ii < KV; ii++) acc += Qp_lds[ii] * W_kv[ii * KV + tid];
        Qk[b * KV + tid] = acc * 0.1f;   // 1/sqrt(100)
    }
}

// ---------------------------------------------------------------------------
// Main: one block per (b,e). All global traffic is fully-contiguous 1KB wave
// loads; v-tile streams via zero-VGPR global_load_lds DMA (max MLP per wave);
// k and W_v use static register batches + LDS-partial redistribution.
// ---------------------------------------------------------------------------
__global__ __launch_bounds__(256, 4) void attn_kernel(
    const float* __restrict__ k,    // [B,E,N,KV]
    const float* __restrict__ v,    // [B,E,N,KV]
    const float* __restrict__ Qk,   // [B,KV] (pre-scaled by 1/sqrt(KV))
    const float* __restrict__ W_v,  // [KV,KV]
    float* __restrict__ out)        // [B,E,KV]
{
    __shared__ __align__(16) float vbuf[N * KV];     // 25.6KB; reused as proj pbuf
    __shared__ float kpbuf[NF4];                     // 6.4KB score partials
    __shared__ __align__(16) float qk_lds[4][KV];    // per-wave Qk copy (no barrier dep)
    __shared__ float att_lds[N];
    __shared__ __align__(16) float agg_lds[KV];

    const int tid  = threadIdx.x;
    const int wid  = tid >> 6;
    const int lane = tid & 63;
    const int be   = blockIdx.x;      // 0..B*E-1
    const int b    = be >> 8;         // /E

    const float4* kb4 = (const float4*)(k + (size_t)be * (N * KV));
    const float4* vb4 = (const float4*)(v + (size_t)be * (N * KV));
    float4* vbuf4 = (float4*)vbuf;

    // ---- issue order: qk (oldest) -> k batch -> v DMA; one latency window ----
    float4 qkreg = make_float4(0.f, 0.f, 0.f, 0.f);
    if (lane < KV / 4) qkreg = ((const float4*)(Qk + b * KV))[lane];

    float4 kk[7];
    #pragma unroll
    for (int r = 0; r < 7; r++) {
        int f = r * 256 + tid;
        kk[r] = (f < NF4) ? kb4[f] : make_float4(0.f, 0.f, 0.f, 0.f);
    }

    // v-tile DMA: zero VGPR, ~26KB in flight per wave
    #pragma unroll
    for (int i = 0; i < 6; i++)
        ASYNC16(vb4 + i * 256 + tid, vbuf4 + i * 256 + (tid & 192));
    if (tid < 64) ASYNC16(vb4 + 1536 + tid, vbuf4 + 1536);

    if (lane < KV / 4) ((float4*)qk_lds[wid])[lane] = qkreg;

    // ---- k dots -> kpbuf (c = f%25 tracked incrementally) ----
    int c = tid % 25;
    const int c0 = c;
    #pragma unroll
    for (int r = 0; r < 7; r++) {
        int f = r * 256 + tid;
        if (f < NF4) {
            float4 qq = ((const float4*)qk_lds[wid])[c];
            kpbuf[f] = dot4(kk[r], qq);
        }
        c += 6; if (c >= 25) c -= 25;
    }
    __syncthreads();   // B1: kpbuf ready; v DMA drained by barrier's vmcnt(0)

    // ---- row-reduce + mask + leaky + softmax (wave 0) ----
    if (tid < N) {
        float s = 0.f;
        #pragma unroll
        for (int j = 0; j < 25; j++) s += kpbuf[tid * 25 + j];
        if (s == 0.0f) s = -10000.0f;        // masked_fill(att==0, -1e4)
        s = (s > 0.0f) ? s : 0.01f * s;      // leaky_relu
        float m = s;
        #pragma unroll
        for (int o = 32; o; o >>= 1) m = fmaxf(m, __shfl_xor(m, o));
        float e = __expf(s - m);
        float su = e;
        #pragma unroll
        for (int o = 32; o; o >>= 1) su += __shfl_xor(su, o);
        float r = e / su;
        if (r == 0.015625f) r = 0.f;         // masked_fill(att==1/N, 0)
        att_lds[tid] = r;
    }
    __syncthreads();   // B2

    // ---- agg[d] = sum_n att[n]*vbuf[n*100+d]; 100 threads, conflict-free ----
    if (tid < KV) {
        float a = 0.f;
        #pragma unroll 8
        for (int n = 0; n < N; n++)
            a += att_lds[n] * vbuf[n * KV + tid];
        agg_lds[tid] = a;
    }
    __syncthreads();   // B3: vbuf dead -> reuse as projection partial buffer

    // ---- projection: flat-contiguous W_v batch, partials into vbuf ----
    {
        const float4* wv4g = (const float4*)W_v;
        float4 wv[10];
        #pragma unroll
        for (int r = 0; r < 10; r++) {
            int f = r * 256 + tid;
            wv[r] = (f < WF4) ? wv4g[f] : make_float4(0.f, 0.f, 0.f, 0.f);
        }
        c = c0;
        #pragma unroll
        for (int r = 0; r < 10; r++) {
            int f = r * 256 + tid;
            if (f < WF4) {
                float4 a = ((const float4*)agg_lds)[c];
                vbuf[f] = dot4(wv[r], a);
            }
            c += 6; if (c >= 25) c -= 25;
        }
    }
    __syncthreads();   // B4

    if (tid < KV) {
        float s = 0.f;
        #pragma unroll
        for (int j = 0; j < 25; j++) s += vbuf[tid * 25 + j];
        out[(size_t)be * KV + tid] = s;
    }
}

extern "C" void kernel_launch(void* const* d_in, const int* in_sizes, int n_in,
                              void* d_out, int out_size, void* d_ws, size_t ws_size,
                              hipStream_t stream) {
    // setup_inputs order: input_ent, q, k, v, W_q, b_q, W_kv, W_v
    const float* q    = (const float*)d_in[1];
    const float* k    = (const float*)d_in[2];
    const float* v    = (const float*)d_in[3];
    const float* W_q  = (const float*)d_in[4];
    const float* b_q  = (const float*)d_in[5];
    const float* W_kv = (const float*)d_in[6];
    const float* W_v  = (const float*)d_in[7];
    float* out  = (float*)d_out;

    float* Qk = (float*)d_ws;            // B*KV = 3200 floats

    prep_kernel<<<B, 256, 0, stream>>>(q, W_q, b_q, W_kv, Qk);
    attn_kernel<<<B * E, 256, 0, stream>>>(k, v, Qk, W_v, out);
}